// Round 1
// baseline (179.467 us; speedup 1.0000x reference)
//
#include <hip/hip_runtime.h>
#include <math.h>

#define BATCH   128
#define N_ATOMS 4096
#define NB      4095
#define NA      4094
#define NT      4093
#define MAX_LEN (5 * NT)            // 20465
#define FSTRIDE ((size_t)MAX_LEN * 9)  // 184185 floats per sample
#define EPSV    1e-8f
#define PARTS   4
#define THREADS 256

__global__ __launch_bounds__(THREADS) void
local_energy_kernel(const float* __restrict__ F,
                    const float* __restrict__ bond_type,   // 15 x 2
                    const float* __restrict__ angle_type,  // 13 x 2
                    const float* __restrict__ tor_type,    // 25 x 2
                    const int*   __restrict__ multiplicity,// 25
                    const float* __restrict__ opt_pars,    // 47
                    float*       __restrict__ out)         // B x 3
{
    __shared__ float scx[N_ATOMS];
    __shared__ float scy[N_ATOMS];
    __shared__ float scz[N_ATOMS];
    __shared__ float sbt[30];
    __shared__ float sat[26];
    __shared__ float stt[50];
    __shared__ float smu[25];
    __shared__ float sred[PARTS == 4 ? 12 : 12]; // 4 waves * 3 partials

    const int blk = blockIdx.x;
    const int s   = blk >> 2;        // sample
    const int p   = blk & 3;         // part
    const int tid = threadIdx.x;
    const float* __restrict__ Fb = F + (size_t)s * FSTRIDE;

    // ---- stage small parameter tables ----
    if (tid < 30)                      sbt[tid]       = bond_type[tid];
    else if (tid >= 32 && tid < 58)    sat[tid - 32]  = angle_type[tid - 32];
    else if (tid >= 64 && tid < 114)   stt[tid - 64]  = tor_type[tid - 64];
    else if (tid >= 128 && tid < 153)  smu[tid - 128] = (float)multiplicity[tid - 128];

    // ---- stage coords (column 5, rows 0..3*N_ATOMS) into LDS planes ----
    for (int l = tid; l < 3 * N_ATOMS; l += THREADS) {
        float v = Fb[(size_t)l * 9 + 5];
        int a = l / 3;
        int c = l - 3 * a;
        if (c == 0)      scx[a] = v;
        else if (c == 1) scy[a] = v;
        else             scz[a] = v;
    }
    __syncthreads();

    float e_bond = 0.0f, e_ang = 0.0f, e_tor = 0.0f;

    // ---- bonds ----
    {
        const int chunk = (NB + PARTS - 1) / PARTS;
        const int lo = p * chunk;
        const int hi = (lo + chunk < NB) ? (lo + chunk) : NB;
        for (int i = lo + tid; i < hi; i += THREADS) {
            const float* bp = Fb + (size_t)(3 * i) * 9 + 6;
            int a0 = (int)bp[0];
            int a1 = (int)bp[9];
            int bt = (int)bp[18];
            float dx = scx[a0] - scx[a1];
            float dy = scy[a0] - scy[a1];
            float dz = scz[a0] - scz[a1];
            float r  = sqrtf(dx*dx + dy*dy + dz*dz + EPSV);
            float k0 = sbt[bt * 2 + 0];
            float r0 = sbt[bt * 2 + 1];
            float t  = r - r0;
            e_bond += k0 * t * t;
        }
    }

    // ---- angles ----
    {
        const int chunk = (NA + PARTS - 1) / PARTS;
        const int lo = p * chunk;
        const int hi = (lo + chunk < NA) ? (lo + chunk) : NA;
        for (int i = lo + tid; i < hi; i += THREADS) {
            const float* ap = Fb + (size_t)(4 * i) * 9 + 7;
            int a0 = (int)ap[0];
            int a1 = (int)ap[9];
            int a2 = (int)ap[18];
            int at = (int)ap[27];
            float v1x = scx[a0] - scx[a1];
            float v1y = scy[a0] - scy[a1];
            float v1z = scz[a0] - scz[a1];
            float v2x = scx[a2] - scx[a1];
            float v2y = scy[a2] - scy[a1];
            float v2z = scz[a2] - scz[a1];
            float d12 = v1x*v2x + v1y*v2y + v1z*v2z;
            float n1  = sqrtf(v1x*v1x + v1y*v1y + v1z*v1z + EPSV);
            float n2  = sqrtf(v2x*v2x + v2y*v2y + v2z*v2z + EPSV);
            float cosang = d12 / (n1 * n2);
            cosang = fminf(fmaxf(cosang, -1.0f + 1e-6f), 1.0f - 1e-6f);
            float theta = acosf(cosang);
            float k0 = sat[at * 2 + 0];
            float t0 = sat[at * 2 + 1];
            float t  = theta - t0;
            e_ang += k0 * t * t;
        }
    }

    // ---- torsions ----
    {
        const int chunk = (NT + PARTS - 1) / PARTS;
        const int lo = p * chunk;
        const int hi = (lo + chunk < NT) ? (lo + chunk) : NT;
        for (int i = lo + tid; i < hi; i += THREADS) {
            const float* tp = Fb + (size_t)(5 * i) * 9 + 8;
            int ai = (int)tp[0];
            int aj = (int)tp[9];
            int ak = (int)tp[18];
            int al = (int)tp[27];
            int tt = (int)tp[36];

            float cix = scx[ai], ciy = scy[ai], ciz = scz[ai];
            float cjx = scx[aj], cjy = scy[aj], cjz = scz[aj];
            float ckx = scx[ak], cky = scy[ak], ckz = scz[ak];
            float clx = scx[al], cly = scy[al], clz = scz[al];

            float b1x = cjx - cix, b1y = cjy - ciy, b1z = cjz - ciz;
            float b2x = ckx - cjx, b2y = cky - cjy, b2z = ckz - cjz;
            float b3x = clx - ckx, b3y = cly - cky, b3z = clz - ckz;

            // n1 = b1 x b2 ; n2 = b2 x b3
            float n1x = b1y*b2z - b1z*b2y;
            float n1y = b1z*b2x - b1x*b2z;
            float n1z = b1x*b2y - b1y*b2x;
            float n2x = b2y*b3z - b2z*b3y;
            float n2y = b2z*b3x - b2x*b3z;
            float n2z = b2x*b3y - b2y*b3x;

            float b2len = sqrtf(b2x*b2x + b2y*b2y + b2z*b2z + EPSV);
            float inv   = 1.0f / b2len;
            float bnx = b2x * inv, bny = b2y * inv, bnz = b2z * inv;

            // m1 = n1 x b2n
            float m1x = n1y*bnz - n1z*bny;
            float m1y = n1z*bnx - n1x*bnz;
            float m1z = n1x*bny - n1y*bnx;

            float sy = m1x*n2x + m1y*n2y + m1z*n2z;
            float sx = n1x*n2x + n1y*n2y + n1z*n2z;
            float phi = atan2f(sy, sx);

            float k0  = stt[tt * 2 + 0];
            float ph0 = stt[tt * 2 + 1];
            float nm  = smu[tt];
            e_tor += k0 * (1.0f + cosf(nm * phi - ph0));
        }
    }

    // ---- reduction: wave shuffle (width 64) -> LDS -> atomicAdd ----
    for (int off = 32; off > 0; off >>= 1) {
        e_bond += __shfl_down(e_bond, off);
        e_ang  += __shfl_down(e_ang,  off);
        e_tor  += __shfl_down(e_tor,  off);
    }
    const int wave = tid >> 6;
    const int lane = tid & 63;
    if (lane == 0) {
        sred[wave * 3 + 0] = e_bond;
        sred[wave * 3 + 1] = e_ang;
        sred[wave * 3 + 2] = e_tor;
    }
    __syncthreads();
    if (tid == 0) {
        float eb = 0.0f, ea = 0.0f, et = 0.0f;
        for (int w = 0; w < THREADS / 64; ++w) {
            eb += sred[w * 3 + 0];
            ea += sred[w * 3 + 1];
            et += sred[w * 3 + 2];
        }
        atomicAdd(&out[s * 3 + 0], opt_pars[0] * eb);
        atomicAdd(&out[s * 3 + 1], opt_pars[1] * ea);
        atomicAdd(&out[s * 3 + 2], opt_pars[2] * et);
    }
}

extern "C" void kernel_launch(void* const* d_in, const int* in_sizes, int n_in,
                              void* d_out, int out_size, void* d_ws, size_t ws_size,
                              hipStream_t stream) {
    const float* F            = (const float*)d_in[0];
    // d_in[1] = lengths (constant, unused)
    const float* bond_type    = (const float*)d_in[2];
    const float* angle_type   = (const float*)d_in[3];
    const float* tor_type     = (const float*)d_in[4];
    const int*   multiplicity = (const int*)  d_in[5];
    const float* opt_pars     = (const float*)d_in[6];
    float* out = (float*)d_out;

    // d_out is poisoned (0xAA) before every call; we accumulate with atomics.
    hipMemsetAsync(out, 0, (size_t)out_size * sizeof(float), stream);

    dim3 grid(BATCH * PARTS);
    dim3 block(THREADS);
    local_energy_kernel<<<grid, block, 0, stream>>>(
        F, bond_type, angle_type, tor_type, multiplicity, opt_pars, out);
}

// Round 2
// 174.024 us; speedup vs baseline: 1.0313x; 1.0313x over previous
//
#include <hip/hip_runtime.h>
#include <math.h>

#define BATCH   128
#define N_ATOMS 4096
#define NB      4095
#define NA      4094
#define NT      4093
#define MAX_LEN (5 * NT)               // 20465
#define FSTRIDE ((size_t)MAX_LEN * 9)  // 184185 floats per sample
#define EPSV    1e-8f
#define PARTS   6                      // 128*6 = 768 blocks = 3 blocks/CU (LDS cap)
#define THREADS 256

__global__ __launch_bounds__(THREADS) void
local_energy_kernel(const float* __restrict__ F,
                    const float* __restrict__ bond_type,   // 15 x 2
                    const float* __restrict__ angle_type,  // 13 x 2
                    const float* __restrict__ tor_type,    // 25 x 2
                    const int*   __restrict__ multiplicity,// 25
                    const float* __restrict__ opt_pars,    // 47
                    float*       __restrict__ out)         // B x 3
{
    __shared__ float scx[N_ATOMS];
    __shared__ float scy[N_ATOMS];
    __shared__ float scz[N_ATOMS];
    __shared__ float sbt[30];
    __shared__ float sat[26];
    __shared__ float stt[50];
    __shared__ float smu[25];
    __shared__ float sred[12];         // 4 waves * 3 partials

    // XCD-swizzle: all PARTS blocks of sample s share blockIdx%8 == s%8, so
    // redundant coord staging hits the same per-XCD L2 instead of refetching.
    const int b   = blockIdx.x;
    const int x   = b & 7;             // XCD slot (heuristic: dispatch round-robins %8)
    const int g   = b >> 3;            // 0..95
    const int s   = (g & 15) * 8 + x;  // sample 0..127, fixed XCD per sample
    const int p   = g >> 4;            // part 0..5
    const int tid = threadIdx.x;
    const float* __restrict__ Fb = F + (size_t)s * FSTRIDE;

    // ---- stage small parameter tables ----
    if (tid < 30)                      sbt[tid]       = bond_type[tid];
    else if (tid >= 32 && tid < 58)    sat[tid - 32]  = angle_type[tid - 32];
    else if (tid >= 64 && tid < 114)   stt[tid - 64]  = tor_type[tid - 64];
    else if (tid >= 128 && tid < 153)  smu[tid - 128] = (float)multiplicity[tid - 128];

    // ---- stage coords: three independent branch-free gather loops ----
    // coords element (atom a, comp c) lives at Fb[27*a + 9*c + 5]
    for (int a = tid; a < N_ATOMS; a += THREADS) {
        const float* cp = Fb + 27 * a;
        float vx = cp[5];
        float vy = cp[14];
        float vz = cp[23];
        scx[a] = vx;
        scy[a] = vy;
        scz[a] = vz;
    }
    __syncthreads();

    float e_bond = 0.0f, e_ang = 0.0f, e_tor = 0.0f;

    // ---- bonds ----
    {
        const int chunk = (NB + PARTS - 1) / PARTS;
        const int lo = p * chunk;
        const int hi = (lo + chunk < NB) ? (lo + chunk) : NB;
        for (int i = lo + tid; i < hi; i += THREADS) {
            const float* bp = Fb + 27 * i + 6;
            int a0 = (int)bp[0];
            int a1 = (int)bp[9];
            int bt = (int)bp[18];
            float dx = scx[a0] - scx[a1];
            float dy = scy[a0] - scy[a1];
            float dz = scz[a0] - scz[a1];
            float r  = sqrtf(dx*dx + dy*dy + dz*dz + EPSV);
            float k0 = sbt[bt * 2 + 0];
            float r0 = sbt[bt * 2 + 1];
            float t  = r - r0;
            e_bond += k0 * t * t;
        }
    }

    // ---- angles ----
    {
        const int chunk = (NA + PARTS - 1) / PARTS;
        const int lo = p * chunk;
        const int hi = (lo + chunk < NA) ? (lo + chunk) : NA;
        for (int i = lo + tid; i < hi; i += THREADS) {
            const float* ap = Fb + 36 * i + 7;
            int a0 = (int)ap[0];
            int a1 = (int)ap[9];
            int a2 = (int)ap[18];
            int at = (int)ap[27];
            float v1x = scx[a0] - scx[a1];
            float v1y = scy[a0] - scy[a1];
            float v1z = scz[a0] - scz[a1];
            float v2x = scx[a2] - scx[a1];
            float v2y = scy[a2] - scy[a1];
            float v2z = scz[a2] - scz[a1];
            float d12 = v1x*v2x + v1y*v2y + v1z*v2z;
            float n1  = sqrtf(v1x*v1x + v1y*v1y + v1z*v1z + EPSV);
            float n2  = sqrtf(v2x*v2x + v2y*v2y + v2z*v2z + EPSV);
            float cosang = d12 / (n1 * n2);
            cosang = fminf(fmaxf(cosang, -1.0f + 1e-6f), 1.0f - 1e-6f);
            float theta = acosf(cosang);
            float k0 = sat[at * 2 + 0];
            float t0 = sat[at * 2 + 1];
            float t  = theta - t0;
            e_ang += k0 * t * t;
        }
    }

    // ---- torsions ----
    {
        const int chunk = (NT + PARTS - 1) / PARTS;
        const int lo = p * chunk;
        const int hi = (lo + chunk < NT) ? (lo + chunk) : NT;
        for (int i = lo + tid; i < hi; i += THREADS) {
            const float* tp = Fb + 45 * i + 8;
            int ai = (int)tp[0];
            int aj = (int)tp[9];
            int ak = (int)tp[18];
            int al = (int)tp[27];
            int tt = (int)tp[36];

            float cix = scx[ai], ciy = scy[ai], ciz = scz[ai];
            float cjx = scx[aj], cjy = scy[aj], cjz = scz[aj];
            float ckx = scx[ak], cky = scy[ak], ckz = scz[ak];
            float clx = scx[al], cly = scy[al], clz = scz[al];

            float b1x = cjx - cix, b1y = cjy - ciy, b1z = cjz - ciz;
            float b2x = ckx - cjx, b2y = cky - cjy, b2z = ckz - cjz;
            float b3x = clx - ckx, b3y = cly - cky, b3z = clz - ckz;

            float n1x = b1y*b2z - b1z*b2y;
            float n1y = b1z*b2x - b1x*b2z;
            float n1z = b1x*b2y - b1y*b2x;
            float n2x = b2y*b3z - b2z*b3y;
            float n2y = b2z*b3x - b2x*b3z;
            float n2z = b2x*b3y - b2y*b3x;

            float b2len = sqrtf(b2x*b2x + b2y*b2y + b2z*b2z + EPSV);
            float inv   = 1.0f / b2len;
            float bnx = b2x * inv, bny = b2y * inv, bnz = b2z * inv;

            float m1x = n1y*bnz - n1z*bny;
            float m1y = n1z*bnx - n1x*bnz;
            float m1z = n1x*bny - n1y*bnx;

            float sy = m1x*n2x + m1y*n2y + m1z*n2z;
            float sx = n1x*n2x + n1y*n2y + n1z*n2z;
            float phi = atan2f(sy, sx);

            float k0  = stt[tt * 2 + 0];
            float ph0 = stt[tt * 2 + 1];
            float nm  = smu[tt];
            e_tor += k0 * (1.0f + cosf(nm * phi - ph0));
        }
    }

    // ---- reduction: wave shuffle (width 64) -> LDS -> atomicAdd ----
    for (int off = 32; off > 0; off >>= 1) {
        e_bond += __shfl_down(e_bond, off);
        e_ang  += __shfl_down(e_ang,  off);
        e_tor  += __shfl_down(e_tor,  off);
    }
    const int wave = tid >> 6;
    const int lane = tid & 63;
    if (lane == 0) {
        sred[wave * 3 + 0] = e_bond;
        sred[wave * 3 + 1] = e_ang;
        sred[wave * 3 + 2] = e_tor;
    }
    __syncthreads();
    if (tid == 0) {
        float eb = 0.0f, ea = 0.0f, et = 0.0f;
        for (int w = 0; w < THREADS / 64; ++w) {
            eb += sred[w * 3 + 0];
            ea += sred[w * 3 + 1];
            et += sred[w * 3 + 2];
        }
        atomicAdd(&out[s * 3 + 0], opt_pars[0] * eb);
        atomicAdd(&out[s * 3 + 1], opt_pars[1] * ea);
        atomicAdd(&out[s * 3 + 2], opt_pars[2] * et);
    }
}

extern "C" void kernel_launch(void* const* d_in, const int* in_sizes, int n_in,
                              void* d_out, int out_size, void* d_ws, size_t ws_size,
                              hipStream_t stream) {
    const float* F            = (const float*)d_in[0];
    // d_in[1] = lengths (constant, unused)
    const float* bond_type    = (const float*)d_in[2];
    const float* angle_type   = (const float*)d_in[3];
    const float* tor_type     = (const float*)d_in[4];
    const int*   multiplicity = (const int*)  d_in[5];
    const float* opt_pars     = (const float*)d_in[6];
    float* out = (float*)d_out;

    hipMemsetAsync(out, 0, (size_t)out_size * sizeof(float), stream);

    dim3 grid(BATCH * PARTS);
    dim3 block(THREADS);
    local_energy_kernel<<<grid, block, 0, stream>>>(
        F, bond_type, angle_type, tor_type, multiplicity, opt_pars, out);
}